// Round 16
// baseline (7309.654 us; speedup 1.0000x reference)
//
#include <hip/hip_runtime.h>
#include <hip/hip_bf16.h>

#define NPTS 8192
#define SDIM 5
#define NBATCH 4
#define NS 4096
#define FEAT 64
#define KNN 3

// ws layout
#define WS_SIDX_OFF   0               // 4*4096*4   = 64 KB
#define WS_KNN_OFF    65536           // 4*4096*3*4 = 192 KB
#define WS_WT_OFF     262144          // 7*4096*4   = 112 KB

typedef float v2f __attribute__((ext_vector_type(2)));

// NOTE on numerics: numpy computes ((((d0*d0+d1*d1)+d2*d2)+d3*d3)+d4*d4) with
// separate mul and add (no FMA). HIP defaults to -ffp-contract=fast; we
// disable contraction with `#pragma clang fp contract(off)` in every distance
// path. No fast-math: ops are never reassociated -> bit-identical to numpy.

__device__ __forceinline__ float sqdist5(float p0, float p1, float p2, float p3, float p4,
                                         float q0, float q1, float q2, float q3, float q4)
{
#pragma clang fp contract(off)
    float d0 = p0 - q0, d1 = p1 - q1, d2 = p2 - q2, d3 = p3 - q3, d4 = p4 - q4;
    float a = d0 * d0 + d1 * d1;
    a = a + d2 * d2;
    a = a + d3 * d3;
    a = a + d4 * d4;
    return a;
}

// ---------------------------------------------------------------------------
// VALU-only 64-lane max via DPP (row_shr 1/2/4/8 + row_bcast15/31).
// ---------------------------------------------------------------------------
__device__ __forceinline__ float wave_max_f32_bcast(float v)
{
    int x;
    x = __builtin_amdgcn_update_dpp(0xFF800000, __float_as_int(v), 0x111, 0xf, 0xf, false);
    v = fmaxf(v, __int_as_float(x));   // row_shr:1
    x = __builtin_amdgcn_update_dpp(0xFF800000, __float_as_int(v), 0x112, 0xf, 0xf, false);
    v = fmaxf(v, __int_as_float(x));   // row_shr:2
    x = __builtin_amdgcn_update_dpp(0xFF800000, __float_as_int(v), 0x114, 0xf, 0xf, false);
    v = fmaxf(v, __int_as_float(x));   // row_shr:4
    x = __builtin_amdgcn_update_dpp(0xFF800000, __float_as_int(v), 0x118, 0xf, 0xf, false);
    v = fmaxf(v, __int_as_float(x));   // row_shr:8
    x = __builtin_amdgcn_update_dpp(0xFF800000, __float_as_int(v), 0x142, 0xf, 0xf, false);
    v = fmaxf(v, __int_as_float(x));   // row_bcast:15
    x = __builtin_amdgcn_update_dpp(0xFF800000, __float_as_int(v), 0x143, 0xf, 0xf, false);
    v = fmaxf(v, __int_as_float(x));   // row_bcast:31
    return __int_as_float(__builtin_amdgcn_readlane(__float_as_int(v), 63));
}

// ---------------------------------------------------------------------------
// Kernel 1 (v15 = v14 + q-from-LDS + relaxed barrier).
// 512 threads (8 waves); thread t owns points [t*16, t*16+16) contiguously.
// Changes vs v14 (both attack the measured ~880cy serial tail):
//  1. Each wave's winning lane publishes its candidate's 5 coords to
//     cc[p][wv] pre-barrier; post-barrier all lanes read the block winner's
//     coords from LDS (~60cy) instead of the bsel-dependent global q-load
//     (~200-300cy L2 latency on the critical path). Bit-identical values.
//  2. __syncthreads -> `s_waitcnt lgkmcnt(0); s_barrier`: no vmcnt(0) drain,
//     so t0's per-step global sidx store no longer stalls the whole block at
//     the barrier. All cross-barrier protocol data (slot, cc) is LDS and is
//     ordered by the lgkmcnt wait; volatile accesses keep compiler order.
// Key: (distbits|msb)<<32 | (0xFFFFFFFF - idx); u64 max == (dist desc, idx asc).
// ---------------------------------------------------------------------------
#define FOR_PAIRS(M) M(0) M(1) M(2) M(3) M(4) M(5) M(6) M(7)

#define BLOCK_SYNC_LGKM() asm volatile("s_waitcnt lgkmcnt(0)\ns_barrier" ::: "memory")

__global__ __launch_bounds__(512, 2)
void fps_kernel(const float* __restrict__ spatial, int* __restrict__ sidx)
{
#pragma clang fp contract(off)
    const int b = blockIdx.x;
    const int t = threadIdx.x;
    const int lane = t & 63;
    const int wv = t >> 6;
    const float* pts = spatial + (size_t)b * NPTS * SDIM;
    const float NEG_INF = -__builtin_inff();

    // 16 contiguous points = 80 floats = 20 aligned float4 (t*320B offset).
    const float4* p4 = (const float4*)(pts + (size_t)t * 80);
    const float4 f0 = p4[0],  f1 = p4[1],  f2 = p4[2],  f3 = p4[3],  f4 = p4[4];
    const float4 f5 = p4[5],  f6 = p4[6],  f7 = p4[7],  f8 = p4[8],  f9 = p4[9];
    const float4 f10 = p4[10], f11 = p4[11], f12 = p4[12], f13 = p4[13], f14 = p4[14];
    const float4 f15 = p4[15], f16 = p4[16], f17 = p4[17], f18 = p4[18], f19 = p4[19];

    // pair J: local points 2J (lo=.x) and 2J+1 (hi=.y)
    v2f px0_0 = {f0.x, f1.y},  px1_0 = {f0.y, f1.z},  px2_0 = {f0.z, f1.w},
        px3_0 = {f0.w, f2.x},  px4_0 = {f1.x, f2.y};
    v2f px0_1 = {f2.z, f3.w},  px1_1 = {f2.w, f4.x},  px2_1 = {f3.x, f4.y},
        px3_1 = {f3.y, f4.z},  px4_1 = {f3.z, f4.w};
    v2f px0_2 = {f5.x, f6.y},  px1_2 = {f5.y, f6.z},  px2_2 = {f5.z, f6.w},
        px3_2 = {f5.w, f7.x},  px4_2 = {f6.x, f7.y};
    v2f px0_3 = {f7.z, f8.w},  px1_3 = {f7.w, f9.x},  px2_3 = {f8.x, f9.y},
        px3_3 = {f8.y, f9.z},  px4_3 = {f8.z, f9.w};
    v2f px0_4 = {f10.x, f11.y}, px1_4 = {f10.y, f11.z}, px2_4 = {f10.z, f11.w},
        px3_4 = {f10.w, f12.x}, px4_4 = {f11.x, f12.y};
    v2f px0_5 = {f12.z, f13.w}, px1_5 = {f12.w, f14.x}, px2_5 = {f13.x, f14.y},
        px3_5 = {f13.y, f14.z}, px4_5 = {f13.z, f14.w};
    v2f px0_6 = {f15.x, f16.y}, px1_6 = {f15.y, f16.z}, px2_6 = {f15.z, f16.w},
        px3_6 = {f15.w, f17.x}, px4_6 = {f16.x, f17.y};
    v2f px0_7 = {f17.z, f18.w}, px1_7 = {f17.w, f19.x}, px2_7 = {f18.x, f19.y},
        px3_7 = {f18.y, f19.z}, px4_7 = {f18.z, f19.w};

#define DECL_DD(J) v2f dd_##J = {__builtin_inff(), __builtin_inff()};
    FOR_PAIRS(DECL_DD)

    if (t == 0) {
        dd_0.x = NEG_INF;                     // point 0 (thread 0, slot 0)
        sidx[b * NS] = 0;
    }

    volatile __shared__ unsigned long long slot[4];
    volatile __shared__ float cc[4][8][5];   // per-wave candidate coords
    if (t == 0) { slot[0] = 0; slot[1] = 0; slot[2] = 0; slot[3] = 0; }
    __syncthreads();

    // initial q = point 0's coords (uniform global load, once)
    float qc0 = pts[0], qc1 = pts[1], qc2 = pts[2], qc3 = pts[3], qc4 = pts[4];

    int bsel = 0;
    for (int step = 1; step < NS; ++step) {
        const int p = step & 3;
        if (t == 0) slot[(step + 2) & 3] = 0;          // reset future slot

        const v2f q0v = {qc0, qc0}, q1v = {qc1, qc1}, q2v = {qc2, qc2},
                  q3v = {qc3, qc3}, q4v = {qc4, qc4};

        float bestv = NEG_INF;
        int   bslot = 0;

#define UPD_PAIR(J)                                                           \
    {                                                                         \
        v2f t0 = px0_##J - q0v;                                               \
        v2f t1 = px1_##J - q1v;                                               \
        v2f t2 = px2_##J - q2v;                                               \
        v2f t3 = px3_##J - q3v;                                               \
        v2f t4 = px4_##J - q4v;                                               \
        v2f a = t0 * t0 + t1 * t1;    /* per-point left-assoc numpy order */  \
        a = a + t2 * t2;                                                      \
        a = a + t3 * t3;                                                      \
        a = a + t4 * t4;                                                      \
        v2f nd;                                                               \
        nd.x = fminf(dd_##J.x, a.x);                                          \
        nd.y = fminf(dd_##J.y, a.y);                                          \
        dd_##J = nd;                                                          \
        if (nd.x > bestv) { bestv = nd.x; bslot = 2 * J; }                    \
        if (nd.y > bestv) { bestv = nd.y; bslot = 2 * J + 1; }                \
    }
        FOR_PAIRS(UPD_PAIR)

        const int besti = (t << 4) | bslot;            // global point index

        // wave argmax: DPP value max; lowest tied lane == lowest global index
        const float maxv = wave_max_f32_bcast(bestv);
        const unsigned long long mask = __ballot(bestv == maxv);
        const int l = __ffsll(mask) - 1;               // uniform across wave
        const int wbest = __builtin_amdgcn_readlane(
            besti, __builtin_amdgcn_readfirstlane(l));

        // winning lane of each wave publishes its candidate's coords
        if (lane == l) {
            volatile float* c = &cc[p][wv][0];
            switch (bslot) {
#define PUB_CASE(J)                                                           \
                case 2 * J:                                                   \
                    c[0] = px0_##J.x; c[1] = px1_##J.x; c[2] = px2_##J.x;     \
                    c[3] = px3_##J.x; c[4] = px4_##J.x; break;                \
                case 2 * J + 1:                                               \
                    c[0] = px0_##J.y; c[1] = px1_##J.y; c[2] = px2_##J.y;     \
                    c[3] = px3_##J.y; c[4] = px4_##J.y; break;
                FOR_PAIRS(PUB_CASE)
            }
        }
        if (lane == 0) {
            const unsigned int kv = (maxv < 0.0f) ? 0u
                                                  : (__float_as_uint(maxv) | 0x80000000u);
            const unsigned long long key =
                ((unsigned long long)kv << 32) |
                (unsigned long long)(0xFFFFFFFFu - (unsigned)wbest);
            atomicMax((unsigned long long*)&slot[p], key);
        }
        BLOCK_SYNC_LGKM();                              // lgkm drain only

        const unsigned long long kk = slot[p];          // broadcast read
        const int sel = (int)(0xFFFFFFFFu - (unsigned int)(kk & 0xFFFFFFFFull));
        bsel = __builtin_amdgcn_readfirstlane(sel);
        if (t == 0) sidx[b * NS + step] = sel;

        // next q = winner's published coords (LDS broadcast read)
        volatile const float* wc = &cc[p][bsel >> 10][0];
        qc0 = wc[0]; qc1 = wc[1]; qc2 = wc[2]; qc3 = wc[3]; qc4 = wc[4];

        const int  jj  = bsel & 15;                     // owner's slot
        const bool own = (bsel >> 4) == t;

#define ZAP_PAIR(J)                                                           \
    {                                                                         \
        if (own && jj == 2 * J)     dd_##J.x = NEG_INF;                       \
        if (own && jj == 2 * J + 1) dd_##J.y = NEG_INF;                       \
    }
        FOR_PAIRS(ZAP_PAIR)
    }
}

// ---------------------------------------------------------------------------
// Kernel 2: kNN (K=3) of each sampled point over the full cloud.
// ---------------------------------------------------------------------------
__global__ __launch_bounds__(256)
void knn_kernel(const float* __restrict__ spatial, const int* __restrict__ sidx,
                int* __restrict__ knn)
{
    const int t   = threadIdx.x;
    const int sl  = t >> 3;
    const int r   = t & 7;
    const int spb = NS / 32;
    const int b   = blockIdx.x / spb;
    const int s   = (blockIdx.x % spb) * 32 + sl;
    const int self = sidx[b * NS + s];
    const float* pts = spatial + (size_t)b * NPTS * SDIM;

    const float q0 = pts[self * SDIM + 0], q1 = pts[self * SDIM + 1],
                q2 = pts[self * SDIM + 2], q3 = pts[self * SDIM + 3],
                q4 = pts[self * SDIM + 4];

    unsigned long long k0 = ~0ull, k1 = ~0ull, k2 = ~0ull;
    for (int i = r; i < NPTS; i += 8) {
        float a = sqdist5(pts[i * SDIM + 0], pts[i * SDIM + 1], pts[i * SDIM + 2],
                          pts[i * SDIM + 3], pts[i * SDIM + 4],
                          q0, q1, q2, q3, q4);
        unsigned long long key = ((unsigned long long)__float_as_uint(a) << 32) |
                                 (unsigned long long)(unsigned)i;
        if (i == self) key = ~0ull;
        if (key < k2) {
            if (key < k1) {
                k2 = k1;
                if (key < k0) { k1 = k0; k0 = key; } else k1 = key;
            } else k2 = key;
        }
    }

    __shared__ unsigned long long sk[256][3];
    sk[t][0] = k0; sk[t][1] = k1; sk[t][2] = k2;
    __syncthreads();

    if (r == 0) {
        unsigned long long b0 = ~0ull, b1 = ~0ull, b2 = ~0ull;
        for (int rr = 0; rr < 8; ++rr) {
#pragma unroll
            for (int m = 0; m < 3; ++m) {
                unsigned long long key = sk[(sl << 3) | rr][m];
                if (key < b2) {
                    if (key < b1) {
                        b2 = b1;
                        if (key < b0) { b1 = b0; b0 = key; } else b1 = key;
                    } else b2 = key;
                }
            }
        }
        const int basei = (b * NS + s) * KNN;
        knn[basei + 0] = (int)(b0 & 0xFFFFFFFFull);
        knn[basei + 1] = (int)(b1 & 0xFFFFFFFFull);
        knn[basei + 2] = (int)(b2 & 0xFFFFFFFFull);
    }
}

// ---------------------------------------------------------------------------
// Kernel 3: gather neighbor features -> second output region (f32).
// ---------------------------------------------------------------------------
__global__ __launch_bounds__(256)
void gather_kernel(const float* __restrict__ x, const int* __restrict__ knn,
                   float* __restrict__ out2)
{
    const long long tid = (long long)blockIdx.x * 256 + threadIdx.x;
    const int       f   = (int)(tid & 63);
    const long long row = tid >> 6;
    const int       idx = knn[row];
    const int       b   = (int)(row / (NS * KNN));
    out2[tid] = x[((size_t)b * NPTS + idx) * FEAT + f];
}

// ---------------------------------------------------------------------------
// Kernel 4a: transpose the 7 weight matrices to [in][out].
// ---------------------------------------------------------------------------
__global__ __launch_bounds__(256)
void transpose_w(const float* __restrict__ w0, const float* __restrict__ w1,
                 const float* __restrict__ w2, const float* __restrict__ w3,
                 const float* __restrict__ w4, const float* __restrict__ w5,
                 const float* __restrict__ w6, float* __restrict__ wt)
{
    const float* w;
    switch (blockIdx.x) {
        case 0: w = w0; break; case 1: w = w1; break; case 2: w = w2; break;
        case 3: w = w3; break; case 4: w = w4; break; case 5: w = w5; break;
        default: w = w6; break;
    }
    float* o = wt + blockIdx.x * 4096;
    for (int e = threadIdx.x; e < 4096; e += 256) {
        const int r = e >> 6, c = e & 63;
        o[c * 64 + r] = w[e];
    }
}

// ---------------------------------------------------------------------------
// Kernel 4b: per-point vector attention MLP chain. One wave per sampled point.
// ---------------------------------------------------------------------------
__global__ __launch_bounds__(256)
void attn_kernel(const float* __restrict__ x, const int* __restrict__ sidx,
                 const float* __restrict__ wt,
                 const float* __restrict__ b_in, const float* __restrict__ b_q,
                 const float* __restrict__ b_k, const float* __restrict__ b_v,
                 const float* __restrict__ b_h1, const float* __restrict__ b_h2,
                 const float* __restrict__ b_out,
                 float* __restrict__ out)
{
    const int lane = threadIdx.x & 63;
    const int wid  = (int)((blockIdx.x * 256 + threadIdx.x) >> 6);
    const int b    = wid >> 12;
    const int si   = sidx[wid];
    const float xs = x[((size_t)b * NPTS + si) * FEAT + lane];

    const float* wt_in  = wt;
    const float* wt_q   = wt + 4096;
    const float* wt_k   = wt + 2 * 4096;
    const float* wt_v   = wt + 3 * 4096;
    const float* wt_h1  = wt + 4 * 4096;
    const float* wt_h2  = wt + 5 * 4096;
    const float* wt_out = wt + 6 * 4096;

    float tv = b_in[lane];
#pragma unroll
    for (int i = 0; i < 64; ++i) tv = fmaf(wt_in[i * 64 + lane], __shfl(xs, i), tv);

    float q = b_q[lane], k = b_k[lane], v = b_v[lane];
#pragma unroll
    for (int i = 0; i < 64; ++i) {
        const float ti = __shfl(tv, i);
        q = fmaf(wt_q[i * 64 + lane], ti, q);
        k = fmaf(wt_k[i * 64 + lane], ti, k);
        v = fmaf(wt_v[i * 64 + lane], ti, v);
    }
    const float d = q - k;
    float h = b_h1[lane];
#pragma unroll
    for (int i = 0; i < 64; ++i) h = fmaf(wt_h1[i * 64 + lane], __shfl(d, i), h);
    h = fmaxf(h, 0.0f);
    float h2 = b_h2[lane];
#pragma unroll
    for (int i = 0; i < 64; ++i) h2 = fmaf(wt_h2[i * 64 + lane], __shfl(h, i), h2);

    float m = h2;
#pragma unroll
    for (int off = 32; off > 0; off >>= 1) m = fmaxf(m, __shfl_xor(m, off));
    const float e = expf(h2 - m);
    float sum = e;
#pragma unroll
    for (int off = 32; off > 0; off >>= 1) sum += __shfl_xor(sum, off);
    const float u = (e / sum) * v;

    float o = b_out[lane];
#pragma unroll
    for (int i = 0; i < 64; ++i) o = fmaf(wt_out[i * 64 + lane], __shfl(u, i), o);
    o += xs;

    out[(size_t)wid * FEAT + lane] = o;
}

// ---------------------------------------------------------------------------
extern "C" void kernel_launch(void* const* d_in, const int* in_sizes, int n_in,
                              void* d_out, int out_size, void* d_ws, size_t ws_size,
                              hipStream_t stream)
{
    const float* x       = (const float*)d_in[0];
    const float* spatial = (const float*)d_in[1];
    const float* w_in    = (const float*)d_in[2];
    const float* b_in    = (const float*)d_in[3];
    const float* w_q     = (const float*)d_in[4];
    const float* b_q     = (const float*)d_in[5];
    const float* w_k     = (const float*)d_in[6];
    const float* b_k     = (const float*)d_in[7];
    const float* w_v     = (const float*)d_in[8];
    const float* b_v     = (const float*)d_in[9];
    const float* w_h1    = (const float*)d_in[10];
    const float* b_h1    = (const float*)d_in[11];
    const float* w_h2    = (const float*)d_in[12];
    const float* b_h2    = (const float*)d_in[13];
    const float* w_out   = (const float*)d_in[14];
    const float* b_out   = (const float*)d_in[15];

    int*   sidx = (int*)((char*)d_ws + WS_SIDX_OFF);
    int*   knn  = (int*)((char*)d_ws + WS_KNN_OFF);
    float* wt   = (float*)((char*)d_ws + WS_WT_OFF);

    float* out  = (float*)d_out;
    float* out2 = out + (size_t)NBATCH * NS * FEAT;

    hipLaunchKernelGGL(fps_kernel, dim3(NBATCH), dim3(512), 0, stream,
                       spatial, sidx);
    hipLaunchKernelGGL(transpose_w, dim3(7), dim3(256), 0, stream,
                       w_in, w_q, w_k, w_v, w_h1, w_h2, w_out, wt);
    hipLaunchKernelGGL(knn_kernel, dim3(NBATCH * NS / 32), dim3(256), 0, stream,
                       spatial, sidx, knn);
    hipLaunchKernelGGL(gather_kernel, dim3(NBATCH * NS * KNN * FEAT / 256), dim3(256),
                       0, stream, x, knn, out2);
    hipLaunchKernelGGL(attn_kernel, dim3(NBATCH * NS * FEAT / 256), dim3(256),
                       0, stream, x, sidx, wt,
                       b_in, b_q, b_k, b_v, b_h1, b_h2, b_out, out);
}

// Round 17
// 5310.358 us; speedup vs baseline: 1.3765x; 1.3765x over previous
//
#include <hip/hip_runtime.h>
#include <hip/hip_bf16.h>

#define NPTS 8192
#define SDIM 5
#define NBATCH 4
#define NS 4096
#define FEAT 64
#define KNN 3

// ws layout
#define WS_SIDX_OFF   0               // 4*4096*4   = 64 KB
#define WS_KNN_OFF    65536           // 4*4096*3*4 = 192 KB
#define WS_WT_OFF     262144          // 7*4096*4   = 112 KB

typedef float v2f __attribute__((ext_vector_type(2)));

// NOTE on numerics: numpy computes ((((d0*d0+d1*d1)+d2*d2)+d3*d3)+d4*d4) with
// separate mul and add (no FMA). HIP defaults to -ffp-contract=fast; we
// disable contraction with `#pragma clang fp contract(off)` in every distance
// path. No fast-math: ops are never reassociated -> bit-identical to numpy.

__device__ __forceinline__ float sqdist5(float p0, float p1, float p2, float p3, float p4,
                                         float q0, float q1, float q2, float q3, float q4)
{
#pragma clang fp contract(off)
    float d0 = p0 - q0, d1 = p1 - q1, d2 = p2 - q2, d3 = p3 - q3, d4 = p4 - q4;
    float a = d0 * d0 + d1 * d1;
    a = a + d2 * d2;
    a = a + d3 * d3;
    a = a + d4 * d4;
    return a;
}

// ---------------------------------------------------------------------------
// VALU-only 64-lane max via DPP (row_shr 1/2/4/8 + row_bcast15/31).
// ---------------------------------------------------------------------------
__device__ __forceinline__ float wave_max_f32_bcast(float v)
{
    int x;
    x = __builtin_amdgcn_update_dpp(0xFF800000, __float_as_int(v), 0x111, 0xf, 0xf, false);
    v = fmaxf(v, __int_as_float(x));   // row_shr:1
    x = __builtin_amdgcn_update_dpp(0xFF800000, __float_as_int(v), 0x112, 0xf, 0xf, false);
    v = fmaxf(v, __int_as_float(x));   // row_shr:2
    x = __builtin_amdgcn_update_dpp(0xFF800000, __float_as_int(v), 0x114, 0xf, 0xf, false);
    v = fmaxf(v, __int_as_float(x));   // row_shr:4
    x = __builtin_amdgcn_update_dpp(0xFF800000, __float_as_int(v), 0x118, 0xf, 0xf, false);
    v = fmaxf(v, __int_as_float(x));   // row_shr:8
    x = __builtin_amdgcn_update_dpp(0xFF800000, __float_as_int(v), 0x142, 0xf, 0xf, false);
    v = fmaxf(v, __int_as_float(x));   // row_bcast:15
    x = __builtin_amdgcn_update_dpp(0xFF800000, __float_as_int(v), 0x143, 0xf, 0xf, false);
    v = fmaxf(v, __int_as_float(x));   // row_bcast:31
    return __int_as_float(__builtin_amdgcn_readlane(__float_as_int(v), 63));
}

// ---------------------------------------------------------------------------
// Kernel 1 (v16 = v14 + ONE change: in-loop barrier drains lgkmcnt only).
// v14 core: 512 threads (8 waves); thread t owns points [t*16, t*16+16)
// contiguously (20 x dwordx4 remat loads), DPP value max + ballot/ffs index
// reduce, LDS atomicMax slot ring, global scalar q-load.
// The ONLY v16 change: __syncthreads() -> `s_waitcnt lgkmcnt(0); s_barrier`.
// __syncthreads' vmcnt(0) drain made wave 0 wait for t0's per-step global
// sidx store to retire (~200-400cy) with all other waves queued behind it.
// No cross-barrier protocol data lives in global memory (slot is LDS; sidx
// is only read by later kernels — dispatch completion guarantees
// visibility), so the vmcnt drain is pure waste. lgkmcnt(0) still orders the
// LDS atomicMax before the barrier; "memory" clobber keeps compiler order.
// Key: (distbits|msb)<<32 | (0xFFFFFFFF - idx); u64 max == (dist desc, idx asc).
// ---------------------------------------------------------------------------
#define FOR_PAIRS(M) M(0) M(1) M(2) M(3) M(4) M(5) M(6) M(7)

#define BLOCK_SYNC_LGKM() asm volatile("s_waitcnt lgkmcnt(0)\ns_barrier" ::: "memory")

__global__ __launch_bounds__(512, 2)
void fps_kernel(const float* __restrict__ spatial, int* __restrict__ sidx)
{
#pragma clang fp contract(off)
    const int b = blockIdx.x;
    const int t = threadIdx.x;
    const int lane = t & 63;
    const float* pts = spatial + (size_t)b * NPTS * SDIM;
    const float NEG_INF = -__builtin_inff();

    // 16 contiguous points = 80 floats = 20 aligned float4 (t*320B offset).
    const float4* p4 = (const float4*)(pts + (size_t)t * 80);
    const float4 f0 = p4[0],  f1 = p4[1],  f2 = p4[2],  f3 = p4[3],  f4 = p4[4];
    const float4 f5 = p4[5],  f6 = p4[6],  f7 = p4[7],  f8 = p4[8],  f9 = p4[9];
    const float4 f10 = p4[10], f11 = p4[11], f12 = p4[12], f13 = p4[13], f14 = p4[14];
    const float4 f15 = p4[15], f16 = p4[16], f17 = p4[17], f18 = p4[18], f19 = p4[19];

    // pair J: local points 2J (lo=.x) and 2J+1 (hi=.y); flat idx lo=10J+k, hi=10J+5+k
    v2f px0_0 = {f0.x, f1.y},  px1_0 = {f0.y, f1.z},  px2_0 = {f0.z, f1.w},
        px3_0 = {f0.w, f2.x},  px4_0 = {f1.x, f2.y};
    v2f px0_1 = {f2.z, f3.w},  px1_1 = {f2.w, f4.x},  px2_1 = {f3.x, f4.y},
        px3_1 = {f3.y, f4.z},  px4_1 = {f3.z, f4.w};
    v2f px0_2 = {f5.x, f6.y},  px1_2 = {f5.y, f6.z},  px2_2 = {f5.z, f6.w},
        px3_2 = {f5.w, f7.x},  px4_2 = {f6.x, f7.y};
    v2f px0_3 = {f7.z, f8.w},  px1_3 = {f7.w, f9.x},  px2_3 = {f8.x, f9.y},
        px3_3 = {f8.y, f9.z},  px4_3 = {f8.z, f9.w};
    v2f px0_4 = {f10.x, f11.y}, px1_4 = {f10.y, f11.z}, px2_4 = {f10.z, f11.w},
        px3_4 = {f10.w, f12.x}, px4_4 = {f11.x, f12.y};
    v2f px0_5 = {f12.z, f13.w}, px1_5 = {f12.w, f14.x}, px2_5 = {f13.x, f14.y},
        px3_5 = {f13.y, f14.z}, px4_5 = {f13.z, f14.w};
    v2f px0_6 = {f15.x, f16.y}, px1_6 = {f15.y, f16.z}, px2_6 = {f15.z, f16.w},
        px3_6 = {f15.w, f17.x}, px4_6 = {f16.x, f17.y};
    v2f px0_7 = {f17.z, f18.w}, px1_7 = {f17.w, f19.x}, px2_7 = {f18.x, f19.y},
        px3_7 = {f18.y, f19.z}, px4_7 = {f18.z, f19.w};

#define DECL_DD(J) v2f dd_##J = {__builtin_inff(), __builtin_inff()};
    FOR_PAIRS(DECL_DD)

    if (t == 0) {
        dd_0.x = NEG_INF;                     // point 0 (thread 0, slot 0)
        sidx[b * NS] = 0;
    }

    __shared__ unsigned long long slot[4];
    if (t == 0) { slot[0] = 0; slot[1] = 0; slot[2] = 0; slot[3] = 0; }
    __syncthreads();

    int bsel = 0;
    for (int step = 1; step < NS; ++step) {
        const int p = step & 3;
        if (t == 0) slot[(step + 2) & 3] = 0;          // reset future slot

        const float* qp = pts + bsel * SDIM;           // uniform -> scalar loads
        const float q0 = qp[0], q1 = qp[1], q2 = qp[2], q3 = qp[3], q4 = qp[4];
        const v2f q0v = {q0, q0}, q1v = {q1, q1}, q2v = {q2, q2},
                  q3v = {q3, q3}, q4v = {q4, q4};

        float bestv = NEG_INF;
        int   bslot = 0;

#define UPD_PAIR(J)                                                           \
    {                                                                         \
        v2f t0 = px0_##J - q0v;                                               \
        v2f t1 = px1_##J - q1v;                                               \
        v2f t2 = px2_##J - q2v;                                               \
        v2f t3 = px3_##J - q3v;                                               \
        v2f t4 = px4_##J - q4v;                                               \
        v2f a = t0 * t0 + t1 * t1;    /* per-point left-assoc numpy order */  \
        a = a + t2 * t2;                                                      \
        a = a + t3 * t3;                                                      \
        a = a + t4 * t4;                                                      \
        v2f nd;                                                               \
        nd.x = fminf(dd_##J.x, a.x);                                          \
        nd.y = fminf(dd_##J.y, a.y);                                          \
        dd_##J = nd;                                                          \
        if (nd.x > bestv) { bestv = nd.x; bslot = 2 * J; }                    \
        if (nd.y > bestv) { bestv = nd.y; bslot = 2 * J + 1; }                \
    }
        FOR_PAIRS(UPD_PAIR)

        const int besti = (t << 4) | bslot;            // global point index

        // wave argmax: DPP value max, then lowest tied lane (== lowest index
        // because per-lane indices are contiguous) via ballot+ffs+readlane.
        const float maxv = wave_max_f32_bcast(bestv);
        const unsigned long long mask = __ballot(bestv == maxv);
        const int l = __ffsll(mask) - 1;               // lowest tied lane
        const int wbest = __builtin_amdgcn_readlane(
            besti, __builtin_amdgcn_readfirstlane(l));

        if (lane == 0) {
            const unsigned int kv = (maxv < 0.0f) ? 0u
                                                  : (__float_as_uint(maxv) | 0x80000000u);
            const unsigned long long key =
                ((unsigned long long)kv << 32) |
                (unsigned long long)(0xFFFFFFFFu - (unsigned)wbest);
            atomicMax(&slot[p], key);
        }
        BLOCK_SYNC_LGKM();                              // lgkm drain only

        const unsigned long long kk = slot[p];          // broadcast read
        const int sel = (int)(0xFFFFFFFFu - (unsigned int)(kk & 0xFFFFFFFFull));
        bsel = __builtin_amdgcn_readfirstlane(sel);
        if (t == 0) sidx[b * NS + step] = sel;

        const int  jj  = bsel & 15;                     // owner's slot
        const bool own = (bsel >> 4) == t;

#define ZAP_PAIR(J)                                                           \
    {                                                                         \
        if (own && jj == 2 * J)     dd_##J.x = NEG_INF;                       \
        if (own && jj == 2 * J + 1) dd_##J.y = NEG_INF;                       \
    }
        FOR_PAIRS(ZAP_PAIR)
    }
}

// ---------------------------------------------------------------------------
// Kernel 2: kNN (K=3) of each sampled point over the full cloud.
// ---------------------------------------------------------------------------
__global__ __launch_bounds__(256)
void knn_kernel(const float* __restrict__ spatial, const int* __restrict__ sidx,
                int* __restrict__ knn)
{
    const int t   = threadIdx.x;
    const int sl  = t >> 3;
    const int r   = t & 7;
    const int spb = NS / 32;
    const int b   = blockIdx.x / spb;
    const int s   = (blockIdx.x % spb) * 32 + sl;
    const int self = sidx[b * NS + s];
    const float* pts = spatial + (size_t)b * NPTS * SDIM;

    const float q0 = pts[self * SDIM + 0], q1 = pts[self * SDIM + 1],
                q2 = pts[self * SDIM + 2], q3 = pts[self * SDIM + 3],
                q4 = pts[self * SDIM + 4];

    unsigned long long k0 = ~0ull, k1 = ~0ull, k2 = ~0ull;
    for (int i = r; i < NPTS; i += 8) {
        float a = sqdist5(pts[i * SDIM + 0], pts[i * SDIM + 1], pts[i * SDIM + 2],
                          pts[i * SDIM + 3], pts[i * SDIM + 4],
                          q0, q1, q2, q3, q4);
        unsigned long long key = ((unsigned long long)__float_as_uint(a) << 32) |
                                 (unsigned long long)(unsigned)i;
        if (i == self) key = ~0ull;
        if (key < k2) {
            if (key < k1) {
                k2 = k1;
                if (key < k0) { k1 = k0; k0 = key; } else k1 = key;
            } else k2 = key;
        }
    }

    __shared__ unsigned long long sk[256][3];
    sk[t][0] = k0; sk[t][1] = k1; sk[t][2] = k2;
    __syncthreads();

    if (r == 0) {
        unsigned long long b0 = ~0ull, b1 = ~0ull, b2 = ~0ull;
        for (int rr = 0; rr < 8; ++rr) {
#pragma unroll
            for (int m = 0; m < 3; ++m) {
                unsigned long long key = sk[(sl << 3) | rr][m];
                if (key < b2) {
                    if (key < b1) {
                        b2 = b1;
                        if (key < b0) { b1 = b0; b0 = key; } else b1 = key;
                    } else b2 = key;
                }
            }
        }
        const int basei = (b * NS + s) * KNN;
        knn[basei + 0] = (int)(b0 & 0xFFFFFFFFull);
        knn[basei + 1] = (int)(b1 & 0xFFFFFFFFull);
        knn[basei + 2] = (int)(b2 & 0xFFFFFFFFull);
    }
}

// ---------------------------------------------------------------------------
// Kernel 3: gather neighbor features -> second output region (f32).
// ---------------------------------------------------------------------------
__global__ __launch_bounds__(256)
void gather_kernel(const float* __restrict__ x, const int* __restrict__ knn,
                   float* __restrict__ out2)
{
    const long long tid = (long long)blockIdx.x * 256 + threadIdx.x;
    const int       f   = (int)(tid & 63);
    const long long row = tid >> 6;
    const int       idx = knn[row];
    const int       b   = (int)(row / (NS * KNN));
    out2[tid] = x[((size_t)b * NPTS + idx) * FEAT + f];
}

// ---------------------------------------------------------------------------
// Kernel 4a: transpose the 7 weight matrices to [in][out].
// ---------------------------------------------------------------------------
__global__ __launch_bounds__(256)
void transpose_w(const float* __restrict__ w0, const float* __restrict__ w1,
                 const float* __restrict__ w2, const float* __restrict__ w3,
                 const float* __restrict__ w4, const float* __restrict__ w5,
                 const float* __restrict__ w6, float* __restrict__ wt)
{
    const float* w;
    switch (blockIdx.x) {
        case 0: w = w0; break; case 1: w = w1; break; case 2: w = w2; break;
        case 3: w = w3; break; case 4: w = w4; break; case 5: w = w5; break;
        default: w = w6; break;
    }
    float* o = wt + blockIdx.x * 4096;
    for (int e = threadIdx.x; e < 4096; e += 256) {
        const int r = e >> 6, c = e & 63;
        o[c * 64 + r] = w[e];
    }
}

// ---------------------------------------------------------------------------
// Kernel 4b: per-point vector attention MLP chain. One wave per sampled point.
// ---------------------------------------------------------------------------
__global__ __launch_bounds__(256)
void attn_kernel(const float* __restrict__ x, const int* __restrict__ sidx,
                 const float* __restrict__ wt,
                 const float* __restrict__ b_in, const float* __restrict__ b_q,
                 const float* __restrict__ b_k, const float* __restrict__ b_v,
                 const float* __restrict__ b_h1, const float* __restrict__ b_h2,
                 const float* __restrict__ b_out,
                 float* __restrict__ out)
{
    const int lane = threadIdx.x & 63;
    const int wid  = (int)((blockIdx.x * 256 + threadIdx.x) >> 6);
    const int b    = wid >> 12;
    const int si   = sidx[wid];
    const float xs = x[((size_t)b * NPTS + si) * FEAT + lane];

    const float* wt_in  = wt;
    const float* wt_q   = wt + 4096;
    const float* wt_k   = wt + 2 * 4096;
    const float* wt_v   = wt + 3 * 4096;
    const float* wt_h1  = wt + 4 * 4096;
    const float* wt_h2  = wt + 5 * 4096;
    const float* wt_out = wt + 6 * 4096;

    float tv = b_in[lane];
#pragma unroll
    for (int i = 0; i < 64; ++i) tv = fmaf(wt_in[i * 64 + lane], __shfl(xs, i), tv);

    float q = b_q[lane], k = b_k[lane], v = b_v[lane];
#pragma unroll
    for (int i = 0; i < 64; ++i) {
        const float ti = __shfl(tv, i);
        q = fmaf(wt_q[i * 64 + lane], ti, q);
        k = fmaf(wt_k[i * 64 + lane], ti, k);
        v = fmaf(wt_v[i * 64 + lane], ti, v);
    }
    const float d = q - k;
    float h = b_h1[lane];
#pragma unroll
    for (int i = 0; i < 64; ++i) h = fmaf(wt_h1[i * 64 + lane], __shfl(d, i), h);
    h = fmaxf(h, 0.0f);
    float h2 = b_h2[lane];
#pragma unroll
    for (int i = 0; i < 64; ++i) h2 = fmaf(wt_h2[i * 64 + lane], __shfl(h, i), h2);

    float m = h2;
#pragma unroll
    for (int off = 32; off > 0; off >>= 1) m = fmaxf(m, __shfl_xor(m, off));
    const float e = expf(h2 - m);
    float sum = e;
#pragma unroll
    for (int off = 32; off > 0; off >>= 1) sum += __shfl_xor(sum, off);
    const float u = (e / sum) * v;

    float o = b_out[lane];
#pragma unroll
    for (int i = 0; i < 64; ++i) o = fmaf(wt_out[i * 64 + lane], __shfl(u, i), o);
    o += xs;

    out[(size_t)wid * FEAT + lane] = o;
}

// ---------------------------------------------------------------------------
extern "C" void kernel_launch(void* const* d_in, const int* in_sizes, int n_in,
                              void* d_out, int out_size, void* d_ws, size_t ws_size,
                              hipStream_t stream)
{
    const float* x       = (const float*)d_in[0];
    const float* spatial = (const float*)d_in[1];
    const float* w_in    = (const float*)d_in[2];
    const float* b_in    = (const float*)d_in[3];
    const float* w_q     = (const float*)d_in[4];
    const float* b_q     = (const float*)d_in[5];
    const float* w_k     = (const float*)d_in[6];
    const float* b_k     = (const float*)d_in[7];
    const float* w_v     = (const float*)d_in[8];
    const float* b_v     = (const float*)d_in[9];
    const float* w_h1    = (const float*)d_in[10];
    const float* b_h1    = (const float*)d_in[11];
    const float* w_h2    = (const float*)d_in[12];
    const float* b_h2    = (const float*)d_in[13];
    const float* w_out   = (const float*)d_in[14];
    const float* b_out   = (const float*)d_in[15];

    int*   sidx = (int*)((char*)d_ws + WS_SIDX_OFF);
    int*   knn  = (int*)((char*)d_ws + WS_KNN_OFF);
    float* wt   = (float*)((char*)d_ws + WS_WT_OFF);

    float* out  = (float*)d_out;
    float* out2 = out + (size_t)NBATCH * NS * FEAT;

    hipLaunchKernelGGL(fps_kernel, dim3(NBATCH), dim3(512), 0, stream,
                       spatial, sidx);
    hipLaunchKernelGGL(transpose_w, dim3(7), dim3(256), 0, stream,
                       w_in, w_q, w_k, w_v, w_h1, w_h2, w_out, wt);
    hipLaunchKernelGGL(knn_kernel, dim3(NBATCH * NS / 32), dim3(256), 0, stream,
                       spatial, sidx, knn);
    hipLaunchKernelGGL(gather_kernel, dim3(NBATCH * NS * KNN * FEAT / 256), dim3(256),
                       0, stream, x, knn, out2);
    hipLaunchKernelGGL(attn_kernel, dim3(NBATCH * NS * FEAT / 256), dim3(256),
                       0, stream, x, sidx, wt,
                       b_in, b_q, b_k, b_v, b_h1, b_h2, b_out, out);
}